// Round 18
// baseline (283.830 us; speedup 1.0000x reference)
//
#include <hip/hip_runtime.h>
#include <hip/hip_bf16.h>

// HisRepItself round 18: conv1+conv2 folded into mega prologue (r17 + convs).
//  Pipeline is now 2 launches: k_prep -> k_mega.
//  Mega prologue per batch: C1 (im2col conv1, Aim in ybf1, out kcs->ybf0 with
//  conv2 swizzle) -> C2 (conv2, W2 frags from L2, key/q f32 -> ybf1) ->
//  attention (key/q from LDS) -> build_x (x_l + bf16 x -> zeroed ybf0) ->
//  layer loop (byte-identical to r13/r17 proven).
//
// Workspace (f32 units): dct 0 | wgT 333312 | gc1wT 1119744 | w1T 1123840
//   w2T 1254912 | bnP 3290624 | aG 3713024 (26*7680 shorts)

typedef __attribute__((ext_vector_type(8))) short short8;
typedef __attribute__((ext_vector_type(4))) float float4v;
typedef __attribute__((ext_vector_type(4))) unsigned uint4v;

#define BNI 0.9999950000374995f

__device__ __forceinline__ short f2bf(float x){
  unsigned u = __float_as_uint(x);
  unsigned r = (u + 0x7fff + ((u >> 16) & 1)) >> 16;
  return (short)r;
}
__device__ __forceinline__ unsigned pk2(float a, float b){
  unsigned r;
  asm("v_cvt_pk_bf16_f32 %0, %1, %2" : "=v"(r) : "v"(a), "v"(b));
  return r;
}
__device__ __forceinline__ float tanh_f(float x){
  x = fminf(fmaxf(x, -9.f), 9.f);
  float e = __expf(2.f * x);
  return (e - 1.f) * __builtin_amdgcn_rcpf(e + 1.f);
}

// ---------------- merged prep kernel (proven) ----------------
// grid: [0,2) dct | [2,1026) wconv1 | [1026,3586) wconv2 | [3586,3970) wgcn
//       [3970,4002) wgc1 | [4002,4782) aG | [4782,6432) bnpack
__global__ __launch_bounds__(256) void k_prep(
    const float* __restrict__ wK1, const float* __restrict__ wQ1,
    const float* __restrict__ wK2, const float* __restrict__ wQ2,
    const float* __restrict__ gw1, const float* __restrict__ gw2,
    const float* __restrict__ gc1_w,
    const float* __restrict__ gc1_att, const float* __restrict__ att1,
    const float* __restrict__ att2, const float* __restrict__ gc7_att,
    const float* __restrict__ g0, const float* __restrict__ be0, const float* __restrict__ b0,
    const float* __restrict__ g1a, const float* __restrict__ be1a, const float* __restrict__ b1a,
    const float* __restrict__ g2a, const float* __restrict__ be2a, const float* __restrict__ b2a,
    float* __restrict__ dct, short* __restrict__ w1T, short* __restrict__ w2T,
    short* __restrict__ wgT, short* __restrict__ gc1wT, short* __restrict__ aG,
    unsigned* __restrict__ bnP)
{
  __shared__ short tle[64][72];
  int bid = blockIdx.x, tid = threadIdx.x;
  if (bid < 2){
    int t = bid*256 + tid;
    if (t < 400){
      int k = t / 20, i = t % 20;
      double w = (k == 0) ? sqrt(1.0/20.0) : sqrt(2.0/20.0);
      dct[t] = (float)(w * cos(3.14159265358979323846 * (i + 0.5) * k / 20.0));
    }
  } else if (bid < 1026){
    int idx = (bid-2)*256 + tid;
    int f = idx >> 9, k = idx & 511;
    float v = 0.f;
    if (k < 396){
      int h = k / 66, c = k - h*66;
      const float* s = (f < 256) ? wK1 : wQ1;
      v = s[((f & 255)*66 + c)*6 + h];
    }
    w1T[idx] = f2bf(v);
  } else if (bid < 3586){
    int idx = (bid-1026)*256 + tid;
    int f = idx / 1280, k = idx - f*1280;
    int h = k >> 8, c = k & 255;
    const float* s = (f < 256) ? wK2 : wQ2;
    w2T[idx] = f2bf(s[((f & 255)*256 + c)*5 + h]);
  } else if (bid < 3970){
    int q = bid - 3586;
    int l = q >> 4, sub = q & 15;
    int kt = (sub >> 2)*64, ft = (sub & 3)*64;
    const float* s = (l < 12) ? (gw1 + l*65536) : (gw2 + (l-12)*65536);
    int c = tid & 63, r4 = tid >> 6;
    #pragma unroll
    for (int p = 0; p < 16; p++){
      int k = p*4 + r4;
      tle[k][c] = f2bf(s[(kt + k)*256 + ft + c]);
    }
    __syncthreads();
    #pragma unroll
    for (int p = 0; p < 16; p++){
      int f = p*4 + r4;
      wgT[l*65536 + (ft + f)*256 + kt + c] = tle[c][f];
    }
  } else if (bid < 4002){
    int idx = (bid-3970)*256 + tid;
    int f = idx >> 5, k = idx & 31;
    gc1wT[idx] = f2bf(k < 20 ? gc1_w[k*256 + f] : 0.f);
  } else if (bid < 4782){
    int idx = (bid-4002)*256 + tid;   // < 26*7680 = 199680 exactly
    int li = idx / 7680, r = idx - li*7680;
    int n = r / 96, m = r - n*96;
    const float* Af;
    if (li == 0) Af = gc1_att;
    else if (li == 25) Af = gc7_att;
    else if (li & 1) Af = att1 + ((li-1)>>1)*4356;
    else             Af = att2 + ((li-2)>>1)*4356;
    aG[idx] = f2bf((n < 66 && m < 66) ? Af[n*66 + m] : 0.f);
  } else {
    int idx = (bid-4782)*256 + tid;
    if (idx < 25*16896){
      int li = idx / 16896, r = idx - li*16896;
      int f = r & 255;
      const float *g, *be, *bi;
      if (li == 0){ g = g0; be = be0; bi = b0; }
      else {
        int l = (li - 1) >> 1;
        if (li & 1){ g = g1a + l*16896; be = be1a + l*16896; bi = b1a + l*256; }
        else       { g = g2a + l*16896; be = be2a + l*16896; bi = b2a + l*256; }
      }
      float sc = g[r] * BNI;
      float sh = bi[f] * sc + be[r];
      bnP[idx] = pk2(sc, sh);
    }
  }
}

// ---------------- mega kernel ----------------
// LDS (byte ^= ((row&15)<<4) for layer tiles):
//   ybf[2] [80 m][512 B] | tT [256 f][256 B] | x_l/xo_l/dct_l f32.
// Prologue reuse: ybf1 = Aim (48x424 bf16) then key/q f32; ybf0 = kcs
// (40x256 bf16, conv2 swizzle) then x_bf; tT = f32 attn scratch.

// MODE: 0 = y_r = v (gc1), 1 = h (no residual), 2 = y_r += v
template<int KSTEPS, int KSTRIDE, int MODE>
__device__ __forceinline__ void layer_step(
    const short* __restrict__ Wg,
    const unsigned* __restrict__ bnl, const short* __restrict__ aGl,
    float4v (&y_r)[2][5], int w, int fl, int g,
    const char* __restrict__ yin, char* __restrict__ yout,
    char* __restrict__ tT_c)
{
  // W rotating prefetch (3 slots)
  const short* wbase = Wg + (w*32 + fl)*KSTRIDE + g*8;
  short8 bw[3][2];
  bw[0][0] = *(const short8*)(wbase);
  bw[0][1] = *(const short8*)(wbase + 16*KSTRIDE);
  if (KSTEPS > 1){
    bw[1][0] = *(const short8*)(wbase + 32);
    bw[1][1] = *(const short8*)(wbase + 16*KSTRIDE + 32);
  }

  // ---- G1: t = y @ W ----
  float4v acc[5][2];
  #pragma unroll
  for (int i=0;i<5;i++){ acc[i][0]=(float4v){0.f,0.f,0.f,0.f}; acc[i][1]=(float4v){0.f,0.f,0.f,0.f}; }
  __builtin_amdgcn_s_setprio(1);
  #pragma unroll
  for (int ks=0; ks<KSTEPS; ks++){
    if (ks + 2 < KSTEPS){
      bw[(ks+2)%3][0] = *(const short8*)(wbase + (ks+2)*32);
      bw[(ks+2)%3][1] = *(const short8*)(wbase + 16*KSTRIDE + (ks+2)*32);
    }
    #pragma unroll
    for (int i=0;i<5;i++){
      int m = i*16 + fl;
      short8 af = *(const short8*)(yin + m*512 + ((ks*64 + g*16) ^ ((m & 15) << 4)));
      acc[i][0] = __builtin_amdgcn_mfma_f32_16x16x32_bf16(af, bw[ks%3][0], acc[i][0], 0,0,0);
      acc[i][1] = __builtin_amdgcn_mfma_f32_16x16x32_bf16(af, bw[ks%3][1], acc[i][1], 0,0,0);
    }
  }
  __builtin_amdgcn_s_setprio(0);

  // A fragments for G2 step 0, issued while acc is packed (acc dying)
  short8 bA[5];
  #pragma unroll
  for (int n2=0;n2<5;n2++)
    bA[n2] = *(const short8*)&aGl[(n2*16 + fl)*96 + g*8];

  // pack acc -> tT (wave-local rows)
  #pragma unroll
  for (int i=0;i<5;i++){
    int mb = (i*16 + g*4)*2;
    #pragma unroll
    for (int n=0;n<2;n++){
      int f = w*32 + n*16 + fl;
      uint2 u; u.x = pk2(acc[i][n][0], acc[i][n][1]); u.y = pk2(acc[i][n][2], acc[i][n][3]);
      *(uint2*)(tT_c + f*256 + (mb ^ ((f & 15) << 4))) = u;
    }
  }

  // ---- G2: o = A @ t ----
  float4v a2[2][5];
  #pragma unroll
  for (int i=0;i<2;i++)
    #pragma unroll
    for (int n=0;n<5;n++) a2[i][n] = (float4v){0.f,0.f,0.f,0.f};
  uint4v bnp0[5];
  #pragma unroll
  for (int ks2=0; ks2<3; ks2++){
    __builtin_amdgcn_s_setprio(1);
    #pragma unroll
    for (int i2=0;i2<2;i2++){
      int f = w*32 + i2*16 + fl;
      short8 af = *(const short8*)(tT_c + f*256 + ((ks2*64 + g*16) ^ ((f & 15) << 4)));
      #pragma unroll
      for (int n2=0;n2<5;n2++)
        a2[i2][n2] = __builtin_amdgcn_mfma_f32_16x16x32_bf16(af, bA[n2], a2[i2][n2], 0,0,0);
    }
    __builtin_amdgcn_s_setprio(0);
    if (ks2 == 1){
      #pragma unroll
      for (int n2=0;n2<5;n2++){
        int n = n2*16 + fl; int ns = (n < 66) ? n : 0;
        bnp0[n2] = *(const uint4v*)&bnl[ns*256 + w*32 + g*4];
      }
    }
    if (ks2 < 2){
      #pragma unroll
      for (int n2=0;n2<5;n2++)
        bA[n2] = *(const short8*)&aGl[(n2*16 + fl)*96 + (ks2+1)*32 + g*8];
    }
  }

  // ---- epilogue: BN + tanh [+res] -> yout ----
  uint4v bnp1[5];
  #pragma unroll
  for (int n2=0;n2<5;n2++){
    int n = n2*16 + fl; int ns = (n < 66) ? n : 0;
    bnp1[n2] = *(const uint4v*)&bnl[ns*256 + w*32 + 16 + g*4];
  }
  #pragma unroll
  for (int i2=0;i2<2;i2++){
    #pragma unroll
    for (int n2=0;n2<5;n2++){
      int n = n2*16 + fl;
      bool nok = (n < 66);
      float vv[4];
      #pragma unroll
      for (int j=0;j<4;j++){
        unsigned u = (i2 == 0) ? bnp0[n2][j] : bnp1[n2][j];
        float sc = __uint_as_float((u & 0xffffu) << 16);
        float sh = __uint_as_float(u & 0xffff0000u);
        float v = a2[i2][n2][j]*sc + sh;
        v = tanh_f(v);
        if (MODE == 0) y_r[i2][n2][j] = v;
        if (MODE == 2){ v += y_r[i2][n2][j]; y_r[i2][n2][j] = v; }
        vv[j] = nok ? v : 0.f;
      }
      int fb2 = (w*32 + i2*16 + g*4)*2;
      uint2 u2; u2.x = pk2(vv[0], vv[1]); u2.y = pk2(vv[2], vv[3]);
      *(uint2*)(yout + n*512 + (fb2 ^ ((n & 15) << 4))) = u2;
    }
  }
  __syncthreads();   // THE barrier
}

__global__ __launch_bounds__(512) void k_mega(const float* __restrict__ src,
    const short* __restrict__ w1T, const short* __restrict__ w2T,
    const short* __restrict__ gc1wT, const short* __restrict__ wgT,
    const short* __restrict__ aG, const unsigned* __restrict__ bnP,
    const float* __restrict__ gc7_w, const float* __restrict__ gc7_b,
    const float* __restrict__ dct, float* __restrict__ out)
{
  __shared__ __align__(16) char ybf_c[81920];   // [2][80][512 B]
  __shared__ __align__(16) char tT_c[65536];
  __shared__ float xo_l[1320];
  __shared__ float x_l[1320];
  __shared__ float dct_l[400];

  int b = blockIdx.x, tid = threadIdx.x;
  int w = tid >> 6, lane = tid & 63, fl = lane & 15, g = lane >> 4;
  char* ybf0 = ybf_c;
  char* ybf1 = ybf_c + 40960;

  // ================= C1: conv1 =================
  short* Aim = (short*)ybf1;   // 48x424 bf16 linear (40704 B)
  for (int idx = tid; idx < 48*424; idx += 512){
    int t = idx / 424, kk = idx - t*424;
    float v = 0.f;
    if (kk < 396 && t < 40){
      int h = kk / 66, c = kk - h*66;
      int row = t + h + ((t >= 35) ? 5 : 0);
      v = src[(b*50 + row)*66 + c] * 1e-3f;
    }
    Aim[idx] = f2bf(v);
  }
  for (int i = tid; i < 400; i += 512) dct_l[i] = dct[i];
  __syncthreads();
  {
    float4v c1[3][4];
    #pragma unroll
    for (int i=0;i<3;i++)
      #pragma unroll
      for (int n=0;n<4;n++) c1[i][n] = (float4v){0.f,0.f,0.f,0.f};
    for (int kt = 0; kt < 13; kt++){
      short8 bw1[4];
      #pragma unroll
      for (int n=0;n<4;n++)
        bw1[n] = *(const short8*)&w1T[(w*64 + n*16 + fl)*512 + kt*32 + g*8];
      #pragma unroll
      for (int i=0;i<3;i++){
        short8 af = *(const short8*)&Aim[(i*16 + fl)*424 + kt*32 + g*8];
        #pragma unroll
        for (int n=0;n<4;n++)
          c1[i][n] = __builtin_amdgcn_mfma_f32_16x16x32_bf16(af, bw1[n], c1[i][n], 0,0,0);
      }
    }
    // epilogue -> kcs in ybf0 (conv2 swizzle: byte = t*512 + (2c ^ ((t&7)<<4)))
    #pragma unroll
    for (int i=0;i<3;i++)
      #pragma unroll
      for (int n=0;n<4;n++)
        #pragma unroll
        for (int j=0;j<4;j++){
          int t = i*16 + g*4 + j;
          int f = w*64 + n*16 + fl;
          float v = fmaxf(c1[i][n][j], 0.f);
          if (t < 35 && f < 256)
            *(short*)(ybf0 + t*512 + ((2*f) ^ ((t & 7) << 4))) = f2bf(v);
          else if (t >= 35 && t < 40 && f >= 256)
            *(short*)(ybf0 + t*512 + ((2*(f - 256)) ^ ((t & 7) << 4))) = f2bf(v);
        }
  }
  __syncthreads();   // kcs ready; Aim dead

  // ================= C2: conv2 =================
  {
    float4v c2[2][4];
    #pragma unroll
    for (int i=0;i<2;i++)
      #pragma unroll
      for (int n=0;n<4;n++) c2[i][n] = (float4v){0.f,0.f,0.f,0.f};
    for (int ks = 0; ks < 40; ks++){
      short8 bw2[4];
      #pragma unroll
      for (int n=0;n<4;n++)
        bw2[n] = *(const short8*)&w2T[(w*64 + n*16 + fl)*1280 + ks*32 + g*8];
      int k = ks*32 + g*8;
      int h = k >> 8, cb = k & 255;
      #pragma unroll
      for (int i=0;i<2;i++){
        int t = i*16 + fl;
        int row = t + h + ((t == 31) ? 4 : 0);
        short8 af = *(const short8*)(ybf0 + row*512 + ((2*cb) ^ ((row & 7) << 4)));
        #pragma unroll
        for (int n=0;n<4;n++)
          c2[i][n] = __builtin_amdgcn_mfma_f32_16x16x32_bf16(af, bw2[n], c2[i][n], 0,0,0);
      }
    }
    // epilogue -> key/q f32 in ybf1 (key[31][256] @0, q[256] @7936 floats)
    float* keyq = (float*)ybf1;
    #pragma unroll
    for (int i=0;i<2;i++)
      #pragma unroll
      for (int n=0;n<4;n++)
        #pragma unroll
        for (int j=0;j<4;j++){
          int t = i*16 + g*4 + j;
          int f = w*64 + n*16 + fl;
          float v = fmaxf(c2[i][n][j], 0.f);
          if (t < 31 && f < 256) keyq[t*256 + f] = v;
          else if (t == 31 && f >= 256) keyq[7936 + f - 256] = v;
        }
  }
  __syncthreads();   // key/q ready; kcs dead

  // ================= attention + build_x =================
  float* scr = (float*)tT_c;   // sred[31][17] @0, a @528, z @560..1880
  const float* keyq = (const float*)ybf1;
  for (int i = tid; i < 10240; i += 512) ((int*)ybf0)[i] = 0;   // zero ybf0
  if (tid < 496){
    int v = tid >> 4, p = tid & 15;
    const float* kr = keyq + v*256 + p*16;
    const float* qr = keyq + 7936 + p*16;
    float s = 0.f;
    #pragma unroll
    for (int o = 0; o < 16; o++) s += qr[o] * kr[o];
    scr[v*17 + p] = s;
  }
  __syncthreads();
  if (tid < 31){
    float s = 1e-15f;
    #pragma unroll
    for (int p = 0; p < 16; p++) s += scr[tid*17 + p];
    scr[528 + tid] = s;
  }
  __syncthreads();
  if (tid < 64){
    float v = (tid < 31) ? scr[528 + tid] : 0.f;
    float tot = v;
    for (int off = 32; off; off >>= 1) tot += __shfl_down(tot, off);
    tot = __shfl(tot, 0);
    if (tid < 31) scr[528 + tid] = v / tot;
  }
  __syncthreads();
  for (int idx = tid; idx < 1320; idx += 512){
    int i = idx / 66, f = idx - (idx/66)*66;
    float s = 0.f;
    for (int v = 0; v < 31; v++) s += scr[528 + v] * src[(b*50 + v + i)*66 + f];
    scr[560 + idx] = s;
  }
  __syncthreads();
  for (int idx = tid; idx < 660; idx += 512){
    int f = idx / 10, k = idx - (idx/10)*10;
    float s1 = 0.f, s2 = 0.f;
    #pragma unroll
    for (int i = 0; i < 20; i++){
      float d = dct_l[k*20 + i];
      int tt = (i < 10) ? (40 + i) : 49;
      s1 += d * src[(b*50 + tt)*66 + f];
      s2 += d * scr[560 + i*66 + f];
    }
    x_l[f*20 + k] = s1;
    x_l[f*20 + 10 + k] = s2;
    *(short*)(ybf0 + f*512 + ((2*k) ^ ((f & 15) << 4))) = f2bf(s1);
    *(short*)(ybf0 + f*512 + ((2*(10 + k)) ^ ((f & 15) << 4))) = f2bf(s2);
  }
  __syncthreads();
  for (int i = tid; i < 4096; i += 512) ((float4v*)tT_c)[i] = (float4v){0.f,0.f,0.f,0.f};
  __syncthreads();
  // ================= end prologue =================

  float4v y_r[2][5];

  layer_step<1,32,0>(gc1wT, bnP, aG, y_r, w, fl, g, ybf0, ybf1, tT_c);
  #pragma unroll 1
  for (int l = 0; l < 12; l++){
    layer_step<8,256,1>(wgT + l*65536, bnP + (1+2*l)*16896, aG + (1+2*l)*7680,
                        y_r, w, fl, g, ybf1, ybf0, tT_c);
    layer_step<8,256,2>(wgT + (12+l)*65536, bnP + (2+2*l)*16896, aG + (2+2*l)*7680,
                        y_r, w, fl, g, ybf0, ybf1, tT_c);
  }

  // ---- gc7 tail ----
  for (int i = tid; i < 2048; i += 512){
    int f = i >> 6, kq = (i & 63)*4;
    float v0=0.f, v1=0.f, v2=0.f, v3=0.f;
    if (f < 20){
      v0 = gc7_w[(kq+0)*20 + f]; v1 = gc7_w[(kq+1)*20 + f];
      v2 = gc7_w[(kq+2)*20 + f]; v3 = gc7_w[(kq+3)*20 + f];
    }
    uint2 u; u.x = pk2(v0, v1); u.y = pk2(v2, v3);
    *(uint2*)(ybf0 + f*512 + ((kq*2) ^ ((f & 15) << 4))) = u;
  }
  __syncthreads();

  float4v at[5][2];
  #pragma unroll
  for (int i=0;i<5;i++){ at[i][0] = (float4v){0.f,0.f,0.f,0.f}; at[i][1] = (float4v){0.f,0.f,0.f,0.f}; }
  #pragma unroll
  for (int ks = 0; ks < 8; ks++){
    short8 bf[2];
    #pragma unroll
    for (int n=0;n<2;n++){
      int f = n*16 + fl;
      bf[n] = *(const short8*)(ybf0 + f*512 + ((ks*64 + g*16) ^ ((f & 15) << 4)));
    }
    #pragma unroll
    for (int i=0;i<5;i++){
      int m = i*16 + fl;
      short8 af = *(const short8*)(ybf1 + m*512 + ((ks*64 + g*16) ^ ((m & 15) << 4)));
      at[i][0] = __builtin_amdgcn_mfma_f32_16x16x32_bf16(af, bf[0], at[i][0], 0,0,0);
      at[i][1] = __builtin_amdgcn_mfma_f32_16x16x32_bf16(af, bf[1], at[i][1], 0,0,0);
    }
  }
  if (w == 0){
    #pragma unroll
    for (int i=0;i<5;i++){
      int mb = (i*16 + g*4)*2;
      #pragma unroll
      for (int n=0;n<2;n++){
        int f = n*16 + fl;
        uint2 u; u.x = pk2(at[i][n][0], at[i][n][1]); u.y = pk2(at[i][n][2], at[i][n][3]);
        *(uint2*)(tT_c + f*256 + (mb ^ ((f & 15) << 4))) = u;
      }
    }
  }
  short8 bAt[15];
  {
    const short* aGt = aG + 25*7680;
    #pragma unroll
    for (int ks=0;ks<3;ks++)
      #pragma unroll
      for (int n2=0;n2<5;n2++)
        bAt[ks*5+n2] = *(const short8*)&aGt[(n2*16 + fl)*96 + ks*32 + g*8];
  }
  __syncthreads();

  float4v a2t[2][5];
  #pragma unroll
  for (int i=0;i<2;i++)
    #pragma unroll
    for (int n=0;n<5;n++) a2t[i][n] = (float4v){0.f,0.f,0.f,0.f};
  #pragma unroll
  for (int ks = 0; ks < 3; ks++){
    #pragma unroll
    for (int i2=0;i2<2;i2++){
      int f = i2*16 + fl;
      short8 af = *(const short8*)(tT_c + f*256 + ((ks*64 + g*16) ^ ((f & 15) << 4)));
      #pragma unroll
      for (int n2=0;n2<5;n2++)
        a2t[i2][n2] = __builtin_amdgcn_mfma_f32_16x16x32_bf16(af, bAt[ks*5+n2], a2t[i2][n2], 0,0,0);
    }
  }
  if (w == 0){
    #pragma unroll
    for (int i2=0;i2<2;i2++){
      #pragma unroll
      for (int n2=0;n2<5;n2++){
        int n = n2*16 + fl;
        #pragma unroll
        for (int j=0;j<4;j++){
          int f = i2*16 + g*4 + j;
          if (f < 20 && n < 66)
            xo_l[n*20 + f] = a2t[i2][n2][j] + gc7_b[f] + x_l[n*20 + f];
        }
      }
    }
  }
  __syncthreads();

  for (int idx = tid; idx < 1320; idx += 512){
    int r = idx / 66, fn = idx % 66;
    float s = 0.f;
    #pragma unroll
    for (int k = 0; k < 10; k++) s += dct_l[k*20 + r] * xo_l[fn*20 + k];
    out[(b*20 + r)*66 + fn] = s;
  }
}

extern "C" void kernel_launch(void* const* d_in, const int* in_sizes, int n_in,
                              void* d_out, int out_size, void* d_ws, size_t ws_size,
                              hipStream_t stream) {
  const float* src      = (const float*)d_in[0];
  const float* convQ_w1 = (const float*)d_in[1];
  const float* convQ_w2 = (const float*)d_in[2];
  const float* convK_w1 = (const float*)d_in[3];
  const float* convK_w2 = (const float*)d_in[4];
  const float* gc1_w    = (const float*)d_in[5];
  const float* gc1_att  = (const float*)d_in[6];
  const float* gc1_b    = (const float*)d_in[7];
  const float* bn1_g    = (const float*)d_in[8];
  const float* bn1_b    = (const float*)d_in[9];
  const float* gcb_w1   = (const float*)d_in[10];
  const float* gcb_att1 = (const float*)d_in[11];
  const float* gcb_b1   = (const float*)d_in[12];
  const float* gcb_bn1g = (const float*)d_in[13];
  const float* gcb_bn1b = (const float*)d_in[14];
  const float* gcb_w2   = (const float*)d_in[15];
  const float* gcb_att2 = (const float*)d_in[16];
  const float* gcb_b2   = (const float*)d_in[17];
  const float* gcb_bn2g = (const float*)d_in[18];
  const float* gcb_bn2b = (const float*)d_in[19];
  const float* gc7_w    = (const float*)d_in[20];
  const float* gc7_att  = (const float*)d_in[21];
  const float* gc7_b    = (const float*)d_in[22];
  float* out = (float*)d_out;

  float* ws    = (float*)d_ws;
  float* dct   = ws;
  short* wgT   = (short*)(ws + 333312);
  short* gc1wT = (short*)(ws + 1119744);
  short* w1T   = (short*)(ws + 1123840);
  short* w2T   = (short*)(ws + 1254912);
  unsigned* bnP= (unsigned*)(ws + 3290624);
  short* aG    = (short*)(ws + 3713024);

  k_prep<<<6432, 256, 0, stream>>>(convK_w1, convQ_w1, convK_w2, convQ_w2,
      gcb_w1, gcb_w2, gc1_w,
      gc1_att, gcb_att1, gcb_att2, gc7_att,
      bn1_g, bn1_b, gc1_b, gcb_bn1g, gcb_bn1b, gcb_b1,
      gcb_bn2g, gcb_bn2b, gcb_b2,
      dct, w1T, w2T, wgT, gc1wT, aG, bnP);

  k_mega<<<128, 512, 0, stream>>>(src, w1T, w2T, gc1wT, wgT, aG, bnP,
      gc7_w, gc7_b, dct, out);
}

// Round 19
// 277.222 us; speedup vs baseline: 1.0238x; 1.0238x over previous
//
#include <hip/hip_runtime.h>
#include <hip/hip_bf16.h>

// HisRepItself round 19: revert to r17 (best: 277.0us total, mega 222us).
//  r18's conv-fold regressed (+62us mega for -55us launches: convs lost
//  their 512-block occupancy). r17 = prep + conv1 + conv2 + mega(attx
//  prologue + single-barrier layer loop + tail).
//
// Workspace (f32 units): dct 0 | wgT 333312 | gc1wT 1119744 | w1T 1123840
//   w2T 1254912 | kc1q 1582592 | key 2237952 | q 3253760 | bnP 3290624
//   aG 3713024 (26*7680 shorts)

typedef __attribute__((ext_vector_type(8))) short short8;
typedef __attribute__((ext_vector_type(4))) float float4v;
typedef __attribute__((ext_vector_type(4))) unsigned uint4v;

#define BNI 0.9999950000374995f

__device__ __forceinline__ short f2bf(float x){
  unsigned u = __float_as_uint(x);
  unsigned r = (u + 0x7fff + ((u >> 16) & 1)) >> 16;
  return (short)r;
}
__device__ __forceinline__ unsigned pk2(float a, float b){
  unsigned r;
  asm("v_cvt_pk_bf16_f32 %0, %1, %2" : "=v"(r) : "v"(a), "v"(b));
  return r;
}
__device__ __forceinline__ float tanh_f(float x){
  x = fminf(fmaxf(x, -9.f), 9.f);
  float e = __expf(2.f * x);
  return (e - 1.f) * __builtin_amdgcn_rcpf(e + 1.f);
}

// ---------------- merged prep kernel (proven) ----------------
// grid: [0,2) dct | [2,1026) wconv1 | [1026,3586) wconv2 | [3586,3970) wgcn
//       [3970,4002) wgc1 | [4002,4782) aG | [4782,6432) bnpack
__global__ __launch_bounds__(256) void k_prep(
    const float* __restrict__ wK1, const float* __restrict__ wQ1,
    const float* __restrict__ wK2, const float* __restrict__ wQ2,
    const float* __restrict__ gw1, const float* __restrict__ gw2,
    const float* __restrict__ gc1_w,
    const float* __restrict__ gc1_att, const float* __restrict__ att1,
    const float* __restrict__ att2, const float* __restrict__ gc7_att,
    const float* __restrict__ g0, const float* __restrict__ be0, const float* __restrict__ b0,
    const float* __restrict__ g1a, const float* __restrict__ be1a, const float* __restrict__ b1a,
    const float* __restrict__ g2a, const float* __restrict__ be2a, const float* __restrict__ b2a,
    float* __restrict__ dct, short* __restrict__ w1T, short* __restrict__ w2T,
    short* __restrict__ wgT, short* __restrict__ gc1wT, short* __restrict__ aG,
    unsigned* __restrict__ bnP)
{
  __shared__ short tle[64][72];
  int bid = blockIdx.x, tid = threadIdx.x;
  if (bid < 2){
    int t = bid*256 + tid;
    if (t < 400){
      int k = t / 20, i = t % 20;
      double w = (k == 0) ? sqrt(1.0/20.0) : sqrt(2.0/20.0);
      dct[t] = (float)(w * cos(3.14159265358979323846 * (i + 0.5) * k / 20.0));
    }
  } else if (bid < 1026){
    int idx = (bid-2)*256 + tid;
    int f = idx >> 9, k = idx & 511;
    float v = 0.f;
    if (k < 396){
      int h = k / 66, c = k - h*66;
      const float* s = (f < 256) ? wK1 : wQ1;
      v = s[((f & 255)*66 + c)*6 + h];
    }
    w1T[idx] = f2bf(v);
  } else if (bid < 3586){
    int idx = (bid-1026)*256 + tid;
    int f = idx / 1280, k = idx - f*1280;
    int h = k >> 8, c = k & 255;
    const float* s = (f < 256) ? wK2 : wQ2;
    w2T[idx] = f2bf(s[((f & 255)*256 + c)*5 + h]);
  } else if (bid < 3970){
    int q = bid - 3586;
    int l = q >> 4, sub = q & 15;
    int kt = (sub >> 2)*64, ft = (sub & 3)*64;
    const float* s = (l < 12) ? (gw1 + l*65536) : (gw2 + (l-12)*65536);
    int c = tid & 63, r4 = tid >> 6;
    #pragma unroll
    for (int p = 0; p < 16; p++){
      int k = p*4 + r4;
      tle[k][c] = f2bf(s[(kt + k)*256 + ft + c]);
    }
    __syncthreads();
    #pragma unroll
    for (int p = 0; p < 16; p++){
      int f = p*4 + r4;
      wgT[l*65536 + (ft + f)*256 + kt + c] = tle[c][f];
    }
  } else if (bid < 4002){
    int idx = (bid-3970)*256 + tid;
    int f = idx >> 5, k = idx & 31;
    gc1wT[idx] = f2bf(k < 20 ? gc1_w[k*256 + f] : 0.f);
  } else if (bid < 4782){
    int idx = (bid-4002)*256 + tid;   // < 26*7680 = 199680 exactly
    int li = idx / 7680, r = idx - li*7680;
    int n = r / 96, m = r - n*96;
    const float* Af;
    if (li == 0) Af = gc1_att;
    else if (li == 25) Af = gc7_att;
    else if (li & 1) Af = att1 + ((li-1)>>1)*4356;
    else             Af = att2 + ((li-2)>>1)*4356;
    aG[idx] = f2bf((n < 66 && m < 66) ? Af[n*66 + m] : 0.f);
  } else {
    int idx = (bid-4782)*256 + tid;
    if (idx < 25*16896){
      int li = idx / 16896, r = idx - li*16896;
      int f = r & 255;
      const float *g, *be, *bi;
      if (li == 0){ g = g0; be = be0; bi = b0; }
      else {
        int l = (li - 1) >> 1;
        if (li & 1){ g = g1a + l*16896; be = be1a + l*16896; bi = b1a + l*256; }
        else       { g = g2a + l*16896; be = be2a + l*16896; bi = b2a + l*256; }
      }
      float sc = g[r] * BNI;
      float sh = bi[f] * sc + be[r];
      bnP[idx] = pk2(sc, sh);
    }
  }
}

// ---------------- conv1 (proven) ----------------
__global__ __launch_bounds__(256) void k_conv1(const float* __restrict__ src,
    const short* __restrict__ w1T, short* __restrict__ kc1q){
  int b = blockIdx.x, ns = blockIdx.y;
  int f0 = ns*128;
  __shared__ short Aim[48*424];
  __shared__ short Wt[128*72];
  int tid = threadIdx.x;
  for (int idx = tid; idx < 48*424; idx += 256){
    int t = idx / 424, kk = idx - t*424;
    float v = 0.f;
    if (kk < 396 && t < 40){
      int h = kk / 66, c = kk - h*66;
      int row = t + h + ((t >= 35) ? 5 : 0);
      v = src[(b*50 + row)*66 + c] * 1e-3f;
    }
    Aim[idx] = f2bf(v);
  }
  int w = tid >> 6, lane = tid & 63, fl = lane & 15, g = lane >> 4;
  float4v acc[3][2];
  #pragma unroll
  for (int i=0;i<3;i++) for (int n=0;n<2;n++) acc[i][n] = (float4v){0.f,0.f,0.f,0.f};
  for (int kt = 0; kt < 416; kt += 64){
    __syncthreads();
    for (int ch = tid; ch < 128*8; ch += 256){
      int r = ch >> 3, kq = ch & 7;
      *(short8*)&Wt[r*72 + kq*8] = *(const short8*)&w1T[(f0 + r)*512 + kt + kq*8];
    }
    __syncthreads();
    int nst = (416 - kt >= 64) ? 2 : 1;
    for (int s = 0; s < nst; s++){
      int k0 = s*32;
      short8 bfr0 = *(const short8*)&Wt[(w*32 + fl)*72 + k0 + g*8];
      short8 bfr1 = *(const short8*)&Wt[(w*32 + 16 + fl)*72 + k0 + g*8];
      #pragma unroll
      for (int i=0;i<3;i++){
        short8 afr = *(const short8*)&Aim[(i*16 + fl)*424 + kt + k0 + g*8];
        acc[i][0] = __builtin_amdgcn_mfma_f32_16x16x32_bf16(afr, bfr0, acc[i][0], 0,0,0);
        acc[i][1] = __builtin_amdgcn_mfma_f32_16x16x32_bf16(afr, bfr1, acc[i][1], 0,0,0);
      }
    }
  }
  #pragma unroll
  for (int i=0;i<3;i++) for (int n=0;n<2;n++) for (int j=0;j<4;j++){
    int t = i*16 + g*4 + j;
    int f = f0 + w*32 + n*16 + fl;
    float v = fmaxf(acc[i][n][j], 0.f);
    if (t < 35 && f < 256) kc1q[(b*40 + t)*256 + f] = f2bf(v);
    else if (t >= 35 && t < 40 && f >= 256) kc1q[(b*40 + t)*256 + (f - 256)] = f2bf(v);
  }
}

// ---------------- conv2 (proven) ----------------
__global__ __launch_bounds__(256) void k_conv2(const short* __restrict__ kc1q,
    const short* __restrict__ w2T, float* __restrict__ key, float* __restrict__ q){
  int b = blockIdx.x, ns = blockIdx.y;
  int f0 = ns*128;
  __shared__ short kcs[40*256];
  __shared__ short Wt[128*136];
  char* kcb = (char*)kcs;
  int tid = threadIdx.x;
  for (int ch = tid; ch < 1280; ch += 256){
    int r = ch >> 5, kq = ch & 31;
    unsigned byte = (unsigned)(r*512 + kq*16) ^ (unsigned)((r & 7) << 4);
    *(short8*)(kcb + byte) = *(const short8*)&kc1q[(b*40 + r)*256 + kq*8];
  }
  int w = tid >> 6, lane = tid & 63, fl = lane & 15, g = lane >> 4;
  float4v acc[2][2];
  #pragma unroll
  for (int i=0;i<2;i++) for (int n=0;n<2;n++) acc[i][n] = (float4v){0.f,0.f,0.f,0.f};
  for (int kt = 0; kt < 1280; kt += 128){
    __syncthreads();
    for (int ch = tid; ch < 128*16; ch += 256){
      int r = ch >> 4, kq = ch & 15;
      *(short8*)&Wt[r*136 + kq*8] = *(const short8*)&w2T[(f0 + r)*1280 + kt + kq*8];
    }
    __syncthreads();
    #pragma unroll
    for (int s = 0; s < 4; s++){
      int k = kt + s*32;
      int h = k >> 8, cb = k & 255;
      short8 bfr0 = *(const short8*)&Wt[(w*32 + fl)*136 + s*32 + g*8];
      short8 bfr1 = *(const short8*)&Wt[(w*32 + 16 + fl)*136 + s*32 + g*8];
      #pragma unroll
      for (int i=0;i<2;i++){
        int t = i*16 + fl;
        int row = t + h + ((t == 31) ? 4 : 0);
        unsigned byte = (unsigned)(row*512 + (cb + g*8)*2) ^ (unsigned)((row & 7) << 4);
        short8 afr = *(const short8*)(kcb + byte);
        acc[i][0] = __builtin_amdgcn_mfma_f32_16x16x32_bf16(afr, bfr0, acc[i][0], 0,0,0);
        acc[i][1] = __builtin_amdgcn_mfma_f32_16x16x32_bf16(afr, bfr1, acc[i][1], 0,0,0);
      }
    }
  }
  #pragma unroll
  for (int i=0;i<2;i++) for (int n=0;n<2;n++) for (int j=0;j<4;j++){
    int t = i*16 + g*4 + j;
    int f = f0 + w*32 + n*16 + fl;
    float v = fmaxf(acc[i][n][j], 0.f);
    if (t < 31 && f < 256) key[(b*31 + t)*256 + f] = v;
    else if (t == 31 && f >= 256) q[b*256 + f - 256] = v;
  }
}

// ---------------- mega kernel: attx prologue + single-barrier layers ----
// LDS (byte ^= ((row&15)<<4)):
//   ybf[2] [80 m][512 B] | tT [256 f][256 B] (wave-local rows; also f32
//   scratch for the attention prologue) | x_l [66*20] f32 for the tail.
// Wave w owns f-slice [32w, 32w+32).

// MODE: 0 = y_r = v (gc1), 1 = h (no residual), 2 = y_r += v
template<int KSTEPS, int KSTRIDE, int MODE>
__device__ __forceinline__ void layer_step(
    const short* __restrict__ Wg,
    const unsigned* __restrict__ bnl, const short* __restrict__ aGl,
    float4v (&y_r)[2][5], int w, int fl, int g,
    const char* __restrict__ yin, char* __restrict__ yout,
    char* __restrict__ tT_c)
{
  // W rotating prefetch (3 slots)
  const short* wbase = Wg + (w*32 + fl)*KSTRIDE + g*8;
  short8 bw[3][2];
  bw[0][0] = *(const short8*)(wbase);
  bw[0][1] = *(const short8*)(wbase + 16*KSTRIDE);
  if (KSTEPS > 1){
    bw[1][0] = *(const short8*)(wbase + 32);
    bw[1][1] = *(const short8*)(wbase + 16*KSTRIDE + 32);
  }

  // ---- G1: t = y @ W ----
  float4v acc[5][2];
  #pragma unroll
  for (int i=0;i<5;i++){ acc[i][0]=(float4v){0.f,0.f,0.f,0.f}; acc[i][1]=(float4v){0.f,0.f,0.f,0.f}; }
  __builtin_amdgcn_s_setprio(1);
  #pragma unroll
  for (int ks=0; ks<KSTEPS; ks++){
    if (ks + 2 < KSTEPS){
      bw[(ks+2)%3][0] = *(const short8*)(wbase + (ks+2)*32);
      bw[(ks+2)%3][1] = *(const short8*)(wbase + 16*KSTRIDE + (ks+2)*32);
    }
    #pragma unroll
    for (int i=0;i<5;i++){
      int m = i*16 + fl;
      short8 af = *(const short8*)(yin + m*512 + ((ks*64 + g*16) ^ ((m & 15) << 4)));
      acc[i][0] = __builtin_amdgcn_mfma_f32_16x16x32_bf16(af, bw[ks%3][0], acc[i][0], 0,0,0);
      acc[i][1] = __builtin_amdgcn_mfma_f32_16x16x32_bf16(af, bw[ks%3][1], acc[i][1], 0,0,0);
    }
  }
  __builtin_amdgcn_s_setprio(0);

  // A fragments for G2 step 0, issued while acc is packed (acc dying)
  short8 bA[5];
  #pragma unroll
  for (int n2=0;n2<5;n2++)
    bA[n2] = *(const short8*)&aGl[(n2*16 + fl)*96 + g*8];

  // pack acc -> tT (wave-local rows; in-wave lgkm ordering suffices)
  #pragma unroll
  for (int i=0;i<5;i++){
    int mb = (i*16 + g*4)*2;
    #pragma unroll
    for (int n=0;n<2;n++){
      int f = w*32 + n*16 + fl;
      uint2 u; u.x = pk2(acc[i][n][0], acc[i][n][1]); u.y = pk2(acc[i][n][2], acc[i][n][3]);
      *(uint2*)(tT_c + f*256 + (mb ^ ((f & 15) << 4))) = u;
    }
  }

  // ---- G2: o = A @ t (no barrier: tT wave-local, A from global) ----
  float4v a2[2][5];
  #pragma unroll
  for (int i=0;i<2;i++)
    #pragma unroll
    for (int n=0;n<5;n++) a2[i][n] = (float4v){0.f,0.f,0.f,0.f};
  uint4v bnp0[5];
  #pragma unroll
  for (int ks2=0; ks2<3; ks2++){
    __builtin_amdgcn_s_setprio(1);
    #pragma unroll
    for (int i2=0;i2<2;i2++){
      int f = w*32 + i2*16 + fl;
      short8 af = *(const short8*)(tT_c + f*256 + ((ks2*64 + g*16) ^ ((f & 15) << 4)));
      #pragma unroll
      for (int n2=0;n2<5;n2++)
        a2[i2][n2] = __builtin_amdgcn_mfma_f32_16x16x32_bf16(af, bA[n2], a2[i2][n2], 0,0,0);
    }
    __builtin_amdgcn_s_setprio(0);
    if (ks2 == 1){
      #pragma unroll
      for (int n2=0;n2<5;n2++){
        int n = n2*16 + fl; int ns = (n < 66) ? n : 0;
        bnp0[n2] = *(const uint4v*)&bnl[ns*256 + w*32 + g*4];
      }
    }
    if (ks2 < 2){
      #pragma unroll
      for (int n2=0;n2<5;n2++)
        bA[n2] = *(const short8*)&aGl[(n2*16 + fl)*96 + (ks2+1)*32 + g*8];
    }
  }

  // ---- epilogue: BN + tanh [+res] -> yout (double-buffered) ----
  uint4v bnp1[5];
  #pragma unroll
  for (int n2=0;n2<5;n2++){
    int n = n2*16 + fl; int ns = (n < 66) ? n : 0;
    bnp1[n2] = *(const uint4v*)&bnl[ns*256 + w*32 + 16 + g*4];
  }
  #pragma unroll
  for (int i2=0;i2<2;i2++){
    #pragma unroll
    for (int n2=0;n2<5;n2++){
      int n = n2*16 + fl;
      bool nok = (n < 66);
      float vv[4];
      #pragma unroll
      for (int j=0;j<4;j++){
        unsigned u = (i2 == 0) ? bnp0[n2][j] : bnp1[n2][j];
        float sc = __uint_as_float((u & 0xffffu) << 16);
        float sh = __uint_as_float(u & 0xffff0000u);
        float v = a2[i2][n2][j]*sc + sh;
        v = tanh_f(v);
        if (MODE == 0) y_r[i2][n2][j] = v;
        if (MODE == 2){ v += y_r[i2][n2][j]; y_r[i2][n2][j] = v; }
        vv[j] = nok ? v : 0.f;
      }
      int fb2 = (w*32 + i2*16 + g*4)*2;
      uint2 u2; u2.x = pk2(vv[0], vv[1]); u2.y = pk2(vv[2], vv[3]);
      *(uint2*)(yout + n*512 + (fb2 ^ ((n & 15) << 4))) = u2;
    }
  }
  __syncthreads();   // THE barrier: yout published for next layer
}

__global__ __launch_bounds__(512) void k_mega(const float* __restrict__ src,
    const float* __restrict__ keyv, const float* __restrict__ qv,
    const short* __restrict__ gc1wT, const short* __restrict__ wgT,
    const short* __restrict__ aG, const unsigned* __restrict__ bnP,
    const float* __restrict__ gc7_w, const float* __restrict__ gc7_b,
    const float* __restrict__ dct, float* __restrict__ out)
{
  __shared__ __align__(16) char ybf_c[81920];   // [2][80][512 B]
  __shared__ __align__(16) char tT_c[65536];
  __shared__ float xo_l[1320];
  __shared__ float x_l[1320];
  __shared__ float dct_l[400];

  int b = blockIdx.x, tid = threadIdx.x;
  int w = tid >> 6, lane = tid & 63, fl = lane & 15, g = lane >> 4;
  char* ybf0 = ybf_c;
  char* ybf1 = ybf_c + 40960;

  // ================= attx prologue (was k_attx) =================
  float* scr = (float*)tT_c;   // sred[31][17] @0, a @528, z @560..1880

  for (int i = tid; i < 10240; i += 512) ((int*)ybf0)[i] = 0;   // zero ybf0
  for (int i = tid; i < 400; i += 512) dct_l[i] = dct[i];
  if (tid < 496){
    int v = tid >> 4, p = tid & 15;
    const float* kr = keyv + (b*31 + v)*256 + p*16;
    const float* qr = qv + b*256 + p*16;
    float s = 0.f;
    #pragma unroll
    for (int o = 0; o < 16; o++) s += qr[o] * kr[o];
    scr[v*17 + p] = s;
  }
  __syncthreads();
  if (tid < 31){
    float s = 1e-15f;
    #pragma unroll
    for (int p = 0; p < 16; p++) s += scr[tid*17 + p];
    scr[528 + tid] = s;
  }
  __syncthreads();
  if (tid < 64){
    float v = (tid < 31) ? scr[528 + tid] : 0.f;
    float tot = v;
    for (int off = 32; off; off >>= 1) tot += __shfl_down(tot, off);
    tot = __shfl(tot, 0);
    if (tid < 31) scr[528 + tid] = v / tot;
  }
  __syncthreads();
  for (int idx = tid; idx < 1320; idx += 512){
    int i = idx / 66, f = idx - (idx/66)*66;
    float s = 0.f;
    for (int v = 0; v < 31; v++) s += scr[528 + v] * src[(b*50 + v + i)*66 + f];
    scr[560 + idx] = s;
  }
  __syncthreads();
  for (int idx = tid; idx < 660; idx += 512){
    int f = idx / 10, k = idx - (idx/10)*10;
    float s1 = 0.f, s2 = 0.f;
    #pragma unroll
    for (int i = 0; i < 20; i++){
      float d = dct_l[k*20 + i];
      int tt = (i < 10) ? (40 + i) : 49;
      s1 += d * src[(b*50 + tt)*66 + f];
      s2 += d * scr[560 + i*66 + f];
    }
    x_l[f*20 + k] = s1;
    x_l[f*20 + 10 + k] = s2;
    *(short*)(ybf0 + f*512 + ((2*k) ^ ((f & 15) << 4))) = f2bf(s1);
    *(short*)(ybf0 + f*512 + ((2*(10 + k)) ^ ((f & 15) << 4))) = f2bf(s2);
  }
  __syncthreads();
  // clear tT (scratch done; also provides zero pad for m in [80,96))
  for (int i = tid; i < 4096; i += 512) ((float4v*)tT_c)[i] = (float4v){0.f,0.f,0.f,0.f};
  __syncthreads();
  // ================= end prologue =================

  float4v y_r[2][5];

  // s=0: gc1 ybf0->ybf1; block l: L1 ybf1->ybf0, L2 ybf0->ybf1. Final: ybf1.
  layer_step<1,32,0>(gc1wT, bnP, aG, y_r, w, fl, g, ybf0, ybf1, tT_c);
  #pragma unroll 1
  for (int l = 0; l < 12; l++){
    layer_step<8,256,1>(wgT + l*65536, bnP + (1+2*l)*16896, aG + (1+2*l)*7680,
                        y_r, w, fl, g, ybf1, ybf0, tT_c);
    layer_step<8,256,2>(wgT + (12+l)*65536, bnP + (2+2*l)*16896, aG + (2+2*l)*7680,
                        y_r, w, fl, g, ybf0, ybf1, tT_c);
  }

  // ---- gc7 tail: stage w7 [32 f][256 k] bf16 into free ybf0 ----
  for (int i = tid; i < 2048; i += 512){
    int f = i >> 6, kq = (i & 63)*4;
    float v0=0.f, v1=0.f, v2=0.f, v3=0.f;
    if (f < 20){
      v0 = gc7_w[(kq+0)*20 + f]; v1 = gc7_w[(kq+1)*20 + f];
      v2 = gc7_w[(kq+2)*20 + f]; v3 = gc7_w[(kq+3)*20 + f];
    }
    uint2 u; u.x = pk2(v0, v1); u.y = pk2(v2, v3);
    *(uint2*)(ybf0 + f*512 + ((kq*2) ^ ((f & 15) << 4))) = u;
  }
  __syncthreads();

  // G1t: t2 = y @ w7 (N=32, K=256), all waves redundant, w0 writes tT
  float4v at[5][2];
  #pragma unroll
  for (int i=0;i<5;i++){ at[i][0] = (float4v){0.f,0.f,0.f,0.f}; at[i][1] = (float4v){0.f,0.f,0.f,0.f}; }
  #pragma unroll
  for (int ks = 0; ks < 8; ks++){
    short8 bf[2];
    #pragma unroll
    for (int n=0;n<2;n++){
      int f = n*16 + fl;
      bf[n] = *(const short8*)(ybf0 + f*512 + ((ks*64 + g*16) ^ ((f & 15) << 4)));
    }
    #pragma unroll
    for (int i=0;i<5;i++){
      int m = i*16 + fl;
      short8 af = *(const short8*)(ybf1 + m*512 + ((ks*64 + g*16) ^ ((m & 15) << 4)));
      at[i][0] = __builtin_amdgcn_mfma_f32_16x16x32_bf16(af, bf[0], at[i][0], 0,0,0);
      at[i][1] = __builtin_amdgcn_mfma_f32_16x16x32_bf16(af, bf[1], at[i][1], 0,0,0);
    }
  }
  if (w == 0){
    #pragma unroll
    for (int i=0;i<5;i++){
      int mb = (i*16 + g*4)*2;
      #pragma unroll
      for (int n=0;n<2;n++){
        int f = n*16 + fl;
        uint2 u; u.x = pk2(at[i][n][0], at[i][n][1]); u.y = pk2(at[i][n][2], at[i][n][3]);
        *(uint2*)(tT_c + f*256 + (mb ^ ((f & 15) << 4))) = u;
      }
    }
  }
  // A7 fragments from global (y_r dead in tail)
  short8 bAt[15];
  {
    const short* aGt = aG + 25*7680;
    #pragma unroll
    for (int ks=0;ks<3;ks++)
      #pragma unroll
      for (int n2=0;n2<5;n2++)
        bAt[ks*5+n2] = *(const short8*)&aGt[(n2*16 + fl)*96 + ks*32 + g*8];
  }
  __syncthreads();

  // G2't: out'[f][n] = t2_T @ A7^T, all waves redundant, w0 epilogue
  float4v a2t[2][5];
  #pragma unroll
  for (int i=0;i<2;i++)
    #pragma unroll
    for (int n=0;n<5;n++) a2t[i][n] = (float4v){0.f,0.f,0.f,0.f};
  #pragma unroll
  for (int ks = 0; ks < 3; ks++){
    #pragma unroll
    for (int i2=0;i2<2;i2++){
      int f = i2*16 + fl;
      short8 af = *(const short8*)(tT_c + f*256 + ((ks*64 + g*16) ^ ((f & 15) << 4)));
      #pragma unroll
      for (int n2=0;n2<5;n2++)
        a2t[i2][n2] = __builtin_amdgcn_mfma_f32_16x16x32_bf16(af, bAt[ks*5+n2], a2t[i2][n2], 0,0,0);
    }
  }
  if (w == 0){
    #pragma unroll
    for (int i2=0;i2<2;i2++){
      #pragma unroll
      for (int n2=0;n2<5;n2++){
        int n = n2*16 + fl;
        #pragma unroll
        for (int j=0;j<4;j++){
          int f = i2*16 + g*4 + j;
          if (f < 20 && n < 66)
            xo_l[n*20 + f] = a2t[i2][n2][j] + gc7_b[f] + x_l[n*20 + f];
        }
      }
    }
  }
  __syncthreads();

  for (int idx = tid; idx < 1320; idx += 512){
    int r = idx / 66, fn = idx % 66;
    float s = 0.f;
    #pragma unroll
    for (int k = 0; k < 10; k++) s += dct_l[k*20 + r] * xo_l[fn*20 + k];
    out[(b*20 + r)*66 + fn] = s;
  }
}

extern "C" void kernel_launch(void* const* d_in, const int* in_sizes, int n_in,
                              void* d_out, int out_size, void* d_ws, size_t ws_size,
                              hipStream_t stream) {
  const float* src      = (const float*)d_in[0];
  const float* convQ_w1 = (const float*)d_in[1];
  const float* convQ_w2 = (const float*)d_in[2];
  const float* convK_w1 = (const float*)d_in[3];
  const float* convK_w2 = (const float*)d_in[4];
  const float* gc1_w    = (const float*)d_in[5];
  const float* gc1_att  = (const float*)d_in[6];
  const float* gc1_b    = (const float*)d_in[7];
  const float* bn1_g    = (const float*)d_in[8];
  const float* bn1_b    = (const float*)d_in[9];
  const float* gcb_w1   = (const float*)d_in[10];
  const float* gcb_att1 = (const float*)d_in[11];
  const float* gcb_b1   = (const float*)d_in[12];
  const float* gcb_bn1g = (const float*)d_in[13];
  const float* gcb_bn1b = (const float*)d_in[14];
  const float* gcb_w2   = (const float*)d_in[15];
  const float* gcb_att2 = (const float*)d_in[16];
  const float* gcb_b2   = (const float*)d_in[17];
  const float* gcb_bn2g = (const float*)d_in[18];
  const float* gcb_bn2b = (const float*)d_in[19];
  const float* gc7_w    = (const float*)d_in[20];
  const float* gc7_att  = (const float*)d_in[21];
  const float* gc7_b    = (const float*)d_in[22];
  float* out = (float*)d_out;

  float* ws    = (float*)d_ws;
  float* dct   = ws;
  short* wgT   = (short*)(ws + 333312);
  short* gc1wT = (short*)(ws + 1119744);
  short* w1T   = (short*)(ws + 1123840);
  short* w2T   = (short*)(ws + 1254912);
  short* kc1q  = (short*)(ws + 1582592);
  float* key   = ws + 2237952;
  float* q     = ws + 3253760;
  unsigned* bnP= (unsigned*)(ws + 3290624);
  short* aG    = (short*)(ws + 3713024);

  k_prep<<<6432, 256, 0, stream>>>(convK_w1, convQ_w1, convK_w2, convQ_w2,
      gcb_w1, gcb_w2, gc1_w,
      gc1_att, gcb_att1, gcb_att2, gc7_att,
      bn1_g, bn1_b, gc1_b, gcb_bn1g, gcb_bn1b, gcb_b1,
      gcb_bn2g, gcb_bn2b, gcb_b2,
      dct, w1T, w2T, wgT, gc1wT, aG, bnP);

  k_conv1<<<dim3(128,4), 256, 0, stream>>>(src, w1T, kc1q);
  k_conv2<<<dim3(128,4), 256, 0, stream>>>(kc1q, w2T, key, q);

  k_mega<<<128, 512, 0, stream>>>(src, key, q, gc1wT, wgT, aG, bnP,
      gc7_w, gc7_b, dct, out);
}